// Round 1
// baseline (1698.769 us; speedup 1.0000x reference)
//
#include <hip/hip_runtime.h>

#define N_NODES 10000
#define N_EDGES 160000
#define IN_CH 128
#define H 64
#define H2 128
#define OUT_CH 112
#define NLAYERS 28

// ---------------- CSR build ----------------
__global__ __launch_bounds__(256) void k_count(const int* __restrict__ ei, int* __restrict__ deg) {
  int e = blockIdx.x * 256 + threadIdx.x;
  atomicAdd(&deg[ei[N_EDGES + e]], 1);   // E = 625*256 exactly
}

__global__ __launch_bounds__(1024) void k_scan(const int* __restrict__ deg, int* __restrict__ offs) {
  __shared__ int sums[1024];
  constexpr int CH = 10; // ceil(10000/1024)
  int t = threadIdx.x;
  int base = t * CH;
  int local[CH];
  int s = 0;
  #pragma unroll
  for (int i = 0; i < CH; i++) {
    int idx = base + i;
    int v = (idx < N_NODES) ? deg[idx] : 0;
    local[i] = s; s += v;
  }
  sums[t] = s;
  __syncthreads();
  for (int off = 1; off < 1024; off <<= 1) {
    int v = (t >= off) ? sums[t - off] : 0;
    __syncthreads();
    sums[t] += v;
    __syncthreads();
  }
  int prev = (t == 0) ? 0 : sums[t - 1];
  #pragma unroll
  for (int i = 0; i < CH; i++) {
    int idx = base + i;
    if (idx < N_NODES) offs[idx] = prev + local[i];
  }
  if (t == 1023) offs[N_NODES] = sums[1023];
}

__global__ __launch_bounds__(256) void k_fill(const int* __restrict__ ei, const int* __restrict__ offs,
                                              int* __restrict__ cur, int* __restrict__ csr) {
  int e = blockIdx.x * 256 + threadIdx.x;
  int d = ei[N_EDGES + e];
  int p = offs[d] + atomicAdd(&cur[d], 1);
  csr[p] = ei[e];
}

// ---------------- encoder: h = x@W+b ; z0 = relu(LN(h; g0,b0)) ----------------
__global__ __launch_bounds__(256) void k_encoder(
    const float* __restrict__ x, const float* __restrict__ Wenc, const float* __restrict__ benc,
    const float* __restrict__ lng, const float* __restrict__ lnb,
    float* __restrict__ h, float* __restrict__ z) {
  __shared__ float xs[16][IN_CH + 4];   // pitch 132
  int t = threadIdx.x;
  int tile = blockIdx.x * 16;
  // stage 16x128 floats = 512 float4
  for (int i = t; i < 512; i += 256) {
    int node = i >> 5;
    int c4 = i & 31;
    float4 v = ((const float4*)x)[(tile + node) * 32 + c4];
    *(float4*)&xs[node][c4 * 4] = v;
  }
  __syncthreads();
  int node = t >> 4;
  int gn = tile + node;
  int cb = t & 15;
  int c0 = cb * 4;
  float a0 = benc[c0], a1 = benc[c0 + 1], a2 = benc[c0 + 2], a3 = benc[c0 + 3];
  #pragma unroll 4
  for (int k = 0; k < IN_CH; k++) {
    float a = xs[node][k];
    float4 w = *(const float4*)&Wenc[k * H + c0];
    a0 = fmaf(a, w.x, a0); a1 = fmaf(a, w.y, a1);
    a2 = fmaf(a, w.z, a2); a3 = fmaf(a, w.w, a3);
  }
  float s = a0 + a1 + a2 + a3;
  float q = a0 * a0 + a1 * a1 + a2 * a2 + a3 * a3;
  #pragma unroll
  for (int m = 1; m < 16; m <<= 1) { s += __shfl_xor(s, m); q += __shfl_xor(q, m); }
  float mu = s * (1.0f / 64.0f);
  float var = q * (1.0f / 64.0f) - mu * mu;
  float rsig = rsqrtf(var + 1e-5f);
  *(float4*)&h[gn * H + c0] = make_float4(a0, a1, a2, a3);
  float z0 = fmaxf(fmaf((a0 - mu) * rsig, lng[c0 + 0], lnb[c0 + 0]), 0.f);
  float z1 = fmaxf(fmaf((a1 - mu) * rsig, lng[c0 + 1], lnb[c0 + 1]), 0.f);
  float z2 = fmaxf(fmaf((a2 - mu) * rsig, lng[c0 + 2], lnb[c0 + 2]), 0.f);
  float z3 = fmaxf(fmaf((a3 - mu) * rsig, lng[c0 + 3], lnb[c0 + 3]), 0.f);
  *(float4*)&z[gn * H + c0] = make_float4(z0, z1, z2, z3);
}

// ---------------- one full GENConv layer ----------------
__global__ __launch_bounds__(256) void k_layer(
    const float* __restrict__ zc, float* __restrict__ zn, float* __restrict__ h,
    const int* __restrict__ offs, const int* __restrict__ csr,
    const float* __restrict__ tvec,
    const float* __restrict__ W1, const float* __restrict__ b1,
    const float* __restrict__ mg, const float* __restrict__ mb,
    const float* __restrict__ W2, const float* __restrict__ b2,
    const float* __restrict__ lngn, const float* __restrict__ lnbn,
    int l) {
  __shared__ float As[16][H + 4];    // out = agg + z  (pitch 68)
  __shared__ float Us[16][H2 + 4];   // relu(LN(u1))   (pitch 132)
  int t = threadIdx.x;
  int tile = blockIdx.x * 16;
  int wave = t >> 6;
  int lane = t & 63;

  // ---- phase A: softmax aggregation (shift-invariant, no max pass needed:
  // logits = (z+1e-7)*t with t=1, z in [0,~8] -> exp bounded, no overflow)
  float tl = tvec[l] * 1.44269504088896340736f;  // t * log2(e)
  #pragma unroll
  for (int i = 0; i < 4; i++) {
    int nl = wave * 4 + i;
    int gn = tile + nl;
    float den = 0.f, acc = 0.f;
    int e0 = offs[gn], e1 = offs[gn + 1];
    for (int e = e0; e < e1; e++) {
      int s = csr[e];
      float v = zc[s * H + lane] + 1e-7f;   // z >= 0 already (post-relu)
      float p = exp2f(v * tl);
      den += p;
      acc = fmaf(p, v, acc);
    }
    float agg = acc / (den + 1e-16f);
    As[nl][lane] = agg + zc[gn * H + lane];
  }
  __syncthreads();

  int node = t >> 4;
  int cb = t & 15;

  // ---- phase B: u1 = out @ W1 + b1 ; act = relu(LN(u1; mg,mb))
  {
    const float* W1l = W1 + (size_t)l * H * H2;
    const float* b1l = b1 + l * H2;
    int c0 = cb * 8;
    float u[8];
    #pragma unroll
    for (int j = 0; j < 8; j++) u[j] = b1l[c0 + j];
    #pragma unroll 4
    for (int k = 0; k < H; k++) {
      float a = As[node][k];
      float4 w0 = *(const float4*)&W1l[k * H2 + c0];
      float4 w1 = *(const float4*)&W1l[k * H2 + c0 + 4];
      u[0] = fmaf(a, w0.x, u[0]); u[1] = fmaf(a, w0.y, u[1]);
      u[2] = fmaf(a, w0.z, u[2]); u[3] = fmaf(a, w0.w, u[3]);
      u[4] = fmaf(a, w1.x, u[4]); u[5] = fmaf(a, w1.y, u[5]);
      u[6] = fmaf(a, w1.z, u[6]); u[7] = fmaf(a, w1.w, u[7]);
    }
    float s = 0.f, q = 0.f;
    #pragma unroll
    for (int j = 0; j < 8; j++) { s += u[j]; q = fmaf(u[j], u[j], q); }
    #pragma unroll
    for (int m = 1; m < 16; m <<= 1) { s += __shfl_xor(s, m); q += __shfl_xor(q, m); }
    float mu = s * (1.0f / 128.0f);
    float var = q * (1.0f / 128.0f) - mu * mu;
    float rsig = rsqrtf(var + 1e-5f);
    const float* mgl = mg + l * H2;
    const float* mbl = mb + l * H2;
    float o[8];
    #pragma unroll
    for (int j = 0; j < 8; j++)
      o[j] = fmaxf(fmaf((u[j] - mu) * rsig, mgl[c0 + j], mbl[c0 + j]), 0.f);
    *(float4*)&Us[node][c0] = make_float4(o[0], o[1], o[2], o[3]);
    *(float4*)&Us[node][c0 + 4] = make_float4(o[4], o[5], o[6], o[7]);
  }
  __syncthreads();

  // ---- phase C: u2 = act @ W2 + b2 ; h += u2 ; phase D: z_next = relu(LN(h))
  {
    const float* W2l = W2 + (size_t)l * H2 * H;
    const float* b2l = b2 + l * H;
    int c0 = cb * 4;
    float u0 = b2l[c0], u1 = b2l[c0 + 1], u2v = b2l[c0 + 2], u3 = b2l[c0 + 3];
    #pragma unroll 4
    for (int j = 0; j < H2; j++) {
      float a = Us[node][j];
      float4 w = *(const float4*)&W2l[j * H + c0];
      u0 = fmaf(a, w.x, u0); u1 = fmaf(a, w.y, u1);
      u2v = fmaf(a, w.z, u2v); u3 = fmaf(a, w.w, u3);
    }
    int gn = tile + node;
    float4 hv = *(const float4*)&h[gn * H + c0];
    float h0 = hv.x + u0, h1 = hv.y + u1, h2 = hv.z + u2v, h3 = hv.w + u3;
    *(float4*)&h[gn * H + c0] = make_float4(h0, h1, h2, h3);
    if (l != NLAYERS - 1) {
      float s = h0 + h1 + h2 + h3;
      float q = h0 * h0 + h1 * h1 + h2 * h2 + h3 * h3;
      #pragma unroll
      for (int m = 1; m < 16; m <<= 1) { s += __shfl_xor(s, m); q += __shfl_xor(q, m); }
      float mu = s * (1.0f / 64.0f);
      float var = q * (1.0f / 64.0f) - mu * mu;
      float rsig = rsqrtf(var + 1e-5f);
      float z0 = fmaxf(fmaf((h0 - mu) * rsig, lngn[c0 + 0], lnbn[c0 + 0]), 0.f);
      float z1 = fmaxf(fmaf((h1 - mu) * rsig, lngn[c0 + 1], lnbn[c0 + 1]), 0.f);
      float z2 = fmaxf(fmaf((h2 - mu) * rsig, lngn[c0 + 2], lnbn[c0 + 2]), 0.f);
      float z3 = fmaxf(fmaf((h3 - mu) * rsig, lngn[c0 + 3], lnbn[c0 + 3]), 0.f);
      *(float4*)&zn[gn * H + c0] = make_float4(z0, z1, z2, z3);
    }
  }
}

// ---------------- head: out = h @ Wh + bh ----------------
__global__ __launch_bounds__(256) void k_head(const float* __restrict__ h, const float* __restrict__ Wh,
                                              const float* __restrict__ bh, float* __restrict__ out) {
  __shared__ float hs[16][H + 4];
  int t = threadIdx.x;
  int tile = blockIdx.x * 16;
  int node = t >> 4;
  int cb = t & 15;
  *(float4*)&hs[node][cb * 4] = *(const float4*)&h[(tile + node) * H + cb * 4];
  __syncthreads();
  float acc[7];
  #pragma unroll
  for (int j = 0; j < 7; j++) acc[j] = bh[cb + 16 * j];
  #pragma unroll 2
  for (int k = 0; k < H; k++) {
    float a = hs[node][k];
    #pragma unroll
    for (int j = 0; j < 7; j++)
      acc[j] = fmaf(a, Wh[k * OUT_CH + cb + 16 * j], acc[j]);
  }
  int gn = tile + node;
  #pragma unroll
  for (int j = 0; j < 7; j++) out[gn * OUT_CH + cb + 16 * j] = acc[j];
}

extern "C" void kernel_launch(void* const* d_in, const int* in_sizes, int n_in,
                              void* d_out, int out_size, void* d_ws, size_t ws_size,
                              hipStream_t stream) {
  (void)in_sizes; (void)n_in; (void)out_size; (void)ws_size;
  const float* x    = (const float*)d_in[0];
  const int*   ei   = (const int*)d_in[1];
  const float* encW = (const float*)d_in[2];
  const float* encb = (const float*)d_in[3];
  const float* lng  = (const float*)d_in[4];
  const float* lnb  = (const float*)d_in[5];
  const float* tv   = (const float*)d_in[6];
  const float* W1   = (const float*)d_in[7];
  const float* b1   = (const float*)d_in[8];
  const float* mg   = (const float*)d_in[9];
  const float* mb   = (const float*)d_in[10];
  const float* W2   = (const float*)d_in[11];
  const float* b2   = (const float*)d_in[12];
  const float* Wh   = (const float*)d_in[13];
  const float* bh   = (const float*)d_in[14];

  char* ws = (char*)d_ws;
  int*   deg  = (int*)(ws + 0);          // N ints
  int*   cur  = (int*)(ws + 40000);      // N ints
  int*   offs = (int*)(ws + 80000);      // N+1 ints
  int*   csr  = (int*)(ws + 120064);     // E ints
  float* h    = (float*)(ws + 760064);   // N*64
  float* z0   = (float*)(ws + 3320064);  // N*64
  float* z1   = (float*)(ws + 5880064);  // N*64

  hipMemsetAsync(ws, 0, 80000, stream);  // deg + cur
  k_count<<<625, 256, 0, stream>>>(ei, deg);
  k_scan<<<1, 1024, 0, stream>>>(deg, offs);
  k_fill<<<625, 256, 0, stream>>>(ei, offs, cur, csr);
  k_encoder<<<625, 256, 0, stream>>>(x, encW, encb, lng, lnb, h, z0);

  float* zc = z0;
  float* znx = z1;
  for (int l = 0; l < NLAYERS; l++) {
    int ln_next = (l + 1 < NLAYERS) ? (l + 1) : l;
    k_layer<<<625, 256, 0, stream>>>(zc, znx, h, offs, csr, tv,
                                     W1, b1, mg, mb, W2, b2,
                                     lng + ln_next * H, lnb + ln_next * H, l);
    float* tmp = zc; zc = znx; znx = tmp;
  }
  k_head<<<625, 256, 0, stream>>>(h, Wh, bh, (float*)d_out);
}

// Round 2
// 636.583 us; speedup vs baseline: 2.6686x; 2.6686x over previous
//
#include <hip/hip_runtime.h>

#define N_NODES 10000
#define N_EDGES 160000
#define IN_CH 128
#define H 64
#define H2 128
#define OUT_CH 112
#define NLAYERS 28

// ---------------- CSR build ----------------
__global__ __launch_bounds__(256) void k_count(const int* __restrict__ ei, int* __restrict__ deg) {
  int e = blockIdx.x * 256 + threadIdx.x;
  atomicAdd(&deg[ei[N_EDGES + e]], 1);   // E = 625*256 exactly
}

__global__ __launch_bounds__(1024) void k_scan(const int* __restrict__ deg, int* __restrict__ offs) {
  __shared__ int sums[1024];
  constexpr int CH = 10;
  int t = threadIdx.x;
  int base = t * CH;
  int local[CH];
  int s = 0;
  #pragma unroll
  for (int i = 0; i < CH; i++) {
    int idx = base + i;
    int v = (idx < N_NODES) ? deg[idx] : 0;
    local[i] = s; s += v;
  }
  sums[t] = s;
  __syncthreads();
  for (int off = 1; off < 1024; off <<= 1) {
    int v = (t >= off) ? sums[t - off] : 0;
    __syncthreads();
    sums[t] += v;
    __syncthreads();
  }
  int prev = (t == 0) ? 0 : sums[t - 1];
  #pragma unroll
  for (int i = 0; i < CH; i++) {
    int idx = base + i;
    if (idx < N_NODES) offs[idx] = prev + local[i];
  }
  if (t == 1023) offs[N_NODES] = sums[1023];
}

__global__ __launch_bounds__(256) void k_fill(const int* __restrict__ ei, const int* __restrict__ offs,
                                              int* __restrict__ cur, int* __restrict__ csr) {
  int e = blockIdx.x * 256 + threadIdx.x;
  int d = ei[N_EDGES + e];
  int p = offs[d] + atomicAdd(&cur[d], 1);
  csr[p] = ei[e];
}

// ---------------- weight packing ----------------
// W1P[l][g][lane][j*2+c] = W1[l][(4g+j)*128 + lane*2+c]   (g<16, lane<64, j<4, c<2)
// W2P[l][g][lane][j]     = W2[l][(4g+j)*64 + lane]        (g<32, lane<64, j<4)
__global__ __launch_bounds__(256) void k_pack(const float* __restrict__ W1, const float* __restrict__ W2,
                                              float* __restrict__ W1P, float* __restrict__ W2P) {
  int l = blockIdx.x;
  const float* w1 = W1 + l * 8192; float* p1 = W1P + l * 8192;
  const float* w2 = W2 + l * 8192; float* p2 = W2P + l * 8192;
  int t = threadIdx.x;
  for (int i = t; i < 8192; i += 256) {
    int g = i >> 9, r = i & 511;
    int lane = r >> 3, j = (r >> 1) & 3, c = r & 1;
    p1[i] = w1[(4 * g + j) * H2 + lane * 2 + c];
  }
  for (int i = t; i < 8192; i += 256) {
    int g = i >> 8, r = i & 255;
    int lane = r >> 2, j = r & 3;
    p2[i] = w2[(4 * g + j) * H + lane];
  }
}

// ---------------- encoder: h = x@W+b ; z0 = relu(LN(h; g0,b0)) ----------------
__global__ __launch_bounds__(256) void k_encoder(
    const float* __restrict__ x, const float* __restrict__ Wenc, const float* __restrict__ benc,
    const float* __restrict__ lng, const float* __restrict__ lnb,
    float* __restrict__ h, float* __restrict__ z) {
  __shared__ float Xs[8][IN_CH];
  int t = threadIdx.x;
  int tile = blockIdx.x * 8;
  {
    int r = t >> 5, c4 = t & 31;
    float4 v = ((const float4*)x)[(tile + r) * 32 + c4];
    *(float4*)&Xs[r][c4 * 4] = v;
  }
  __syncthreads();
  int lane = t & 63;
  int wave = __builtin_amdgcn_readfirstlane(t >> 6);
  int n0 = wave * 2;
  float b = benc[lane];
  float a0 = b, a1 = b;
  #pragma unroll
  for (int k = 0; k < IN_CH; k += 4) {
    float4 X0 = *(float4*)&Xs[n0][k];
    float4 X1 = *(float4*)&Xs[n0 + 1][k];
    float w0 = Wenc[(k + 0) * H + lane];
    float w1 = Wenc[(k + 1) * H + lane];
    float w2 = Wenc[(k + 2) * H + lane];
    float w3 = Wenc[(k + 3) * H + lane];
    a0 = fmaf(X0.x, w0, a0); a0 = fmaf(X0.y, w1, a0); a0 = fmaf(X0.z, w2, a0); a0 = fmaf(X0.w, w3, a0);
    a1 = fmaf(X1.x, w0, a1); a1 = fmaf(X1.y, w1, a1); a1 = fmaf(X1.z, w2, a1); a1 = fmaf(X1.w, w3, a1);
  }
  float g = lng[lane], bb = lnb[lane];
  #pragma unroll
  for (int i = 0; i < 2; i++) {
    float a = (i == 0) ? a0 : a1;
    float s = a, q = a * a;
    #pragma unroll
    for (int m = 1; m < 64; m <<= 1) { s += __shfl_xor(s, m); q += __shfl_xor(q, m); }
    float mu = s * (1.0f / 64.0f);
    float var = q * (1.0f / 64.0f) - mu * mu;
    float rs = rsqrtf(var + 1e-5f);
    int gn = tile + n0 + i;
    h[gn * H + lane] = a;
    z[gn * H + lane] = fmaxf(fmaf((a - mu) * rs, g, bb), 0.f);
  }
}

// ---------------- one full GENConv layer ----------------
__global__ __launch_bounds__(256) void k_layer(
    const float* __restrict__ zc, float* __restrict__ zn, float* __restrict__ h,
    const int* __restrict__ offs, const int* __restrict__ csr,
    const float* __restrict__ tvec,
    const float* __restrict__ W1P, const float* __restrict__ b1,
    const float* __restrict__ mg, const float* __restrict__ mb,
    const float* __restrict__ W2P, const float* __restrict__ b2,
    const float* __restrict__ lngn, const float* __restrict__ lnbn,
    int l) {
  __shared__ float As[8][H];
  __shared__ float Us[8][H2];
  int t = threadIdx.x;
  int lane = t & 63;
  int wave = __builtin_amdgcn_readfirstlane(t >> 6);
  int nb0 = blockIdx.x * 8 + wave * 2;

  float tl = tvec[l] * 1.44269504088896340736f;
  // ---- phase A: softmax aggregation, 2 nodes per wave, lane = channel
  #pragma unroll
  for (int i = 0; i < 2; i++) {
    int gn = nb0 + i;
    int e0 = offs[gn], e1 = offs[gn + 1];
    float d0 = 0.f, d1 = 0.f, d2 = 0.f, d3 = 0.f;
    float a0 = 0.f, a1 = 0.f, a2 = 0.f, a3 = 0.f;
    int e = e0;
    for (; e + 4 <= e1; e += 4) {
      int s0 = csr[e], s1 = csr[e + 1], s2 = csr[e + 2], s3 = csr[e + 3];
      float v0 = zc[s0 * H + lane] + 1e-7f;
      float v1 = zc[s1 * H + lane] + 1e-7f;
      float v2 = zc[s2 * H + lane] + 1e-7f;
      float v3 = zc[s3 * H + lane] + 1e-7f;
      float p0 = exp2f(v0 * tl), p1 = exp2f(v1 * tl);
      float p2 = exp2f(v2 * tl), p3 = exp2f(v3 * tl);
      d0 += p0; d1 += p1; d2 += p2; d3 += p3;
      a0 = fmaf(p0, v0, a0); a1 = fmaf(p1, v1, a1);
      a2 = fmaf(p2, v2, a2); a3 = fmaf(p3, v3, a3);
    }
    for (; e < e1; e++) {
      int s0 = csr[e];
      float v0 = zc[s0 * H + lane] + 1e-7f;
      float p0 = exp2f(v0 * tl);
      d0 += p0; a0 = fmaf(p0, v0, a0);
    }
    float den = (d0 + d1) + (d2 + d3);
    float acc = (a0 + a1) + (a2 + a3);
    As[wave * 2 + i][lane] = acc / (den + 1e-16f) + zc[gn * H + lane];
  }
  __syncthreads();

  // ---- phase B: u1 = As @ W1 + b1 ; Us = relu(LN(u1; mg,mb))
  {
    const float* W1Pl = W1P + (size_t)l * (H * H2);
    const float* b1l = b1 + l * H2;
    int c0 = lane * 2;
    float bb0 = b1l[c0], bb1 = b1l[c0 + 1];
    float u00 = bb0, u01 = bb1, u10 = bb0, u11 = bb1;
    #pragma unroll
    for (int g = 0; g < 16; g++) {
      float4 A0 = *(float4*)&As[wave * 2 + 0][g * 4];
      float4 A1 = *(float4*)&As[wave * 2 + 1][g * 4];
      float4 wa = *(const float4*)&W1Pl[g * 512 + lane * 8];
      float4 wb = *(const float4*)&W1Pl[g * 512 + lane * 8 + 4];
      u00 = fmaf(A0.x, wa.x, u00); u01 = fmaf(A0.x, wa.y, u01);
      u00 = fmaf(A0.y, wa.z, u00); u01 = fmaf(A0.y, wa.w, u01);
      u00 = fmaf(A0.z, wb.x, u00); u01 = fmaf(A0.z, wb.y, u01);
      u00 = fmaf(A0.w, wb.z, u00); u01 = fmaf(A0.w, wb.w, u01);
      u10 = fmaf(A1.x, wa.x, u10); u11 = fmaf(A1.x, wa.y, u11);
      u10 = fmaf(A1.y, wa.z, u10); u11 = fmaf(A1.y, wa.w, u11);
      u10 = fmaf(A1.z, wb.x, u10); u11 = fmaf(A1.z, wb.y, u11);
      u10 = fmaf(A1.w, wb.z, u10); u11 = fmaf(A1.w, wb.w, u11);
    }
    float s0 = u00 + u01, q0 = u00 * u00 + u01 * u01;
    float s1 = u10 + u11, q1 = u10 * u10 + u11 * u11;
    #pragma unroll
    for (int m = 1; m < 64; m <<= 1) {
      s0 += __shfl_xor(s0, m); q0 += __shfl_xor(q0, m);
      s1 += __shfl_xor(s1, m); q1 += __shfl_xor(q1, m);
    }
    float mu0 = s0 * (1.0f / 128.0f), mu1 = s1 * (1.0f / 128.0f);
    float rs0 = rsqrtf(q0 * (1.0f / 128.0f) - mu0 * mu0 + 1e-5f);
    float rs1 = rsqrtf(q1 * (1.0f / 128.0f) - mu1 * mu1 + 1e-5f);
    const float* mgl = mg + l * H2;
    const float* mbl = mb + l * H2;
    float g0 = mgl[c0], g1 = mgl[c0 + 1], h0 = mbl[c0], h1 = mbl[c0 + 1];
    float o00 = fmaxf(fmaf((u00 - mu0) * rs0, g0, h0), 0.f);
    float o01 = fmaxf(fmaf((u01 - mu0) * rs0, g1, h1), 0.f);
    float o10 = fmaxf(fmaf((u10 - mu1) * rs1, g0, h0), 0.f);
    float o11 = fmaxf(fmaf((u11 - mu1) * rs1, g1, h1), 0.f);
    *(float2*)&Us[wave * 2 + 0][c0] = make_float2(o00, o01);
    *(float2*)&Us[wave * 2 + 1][c0] = make_float2(o10, o11);
  }
  __syncthreads();

  // ---- phase C: u2 = Us @ W2 + b2 ; h += u2 ; phase D: z_next = relu(LN(h))
  {
    const float* W2Pl = W2P + (size_t)l * (H2 * H);
    const float* b2l = b2 + l * H;
    float bb = b2l[lane];
    float v0 = bb, v1 = bb;
    #pragma unroll
    for (int g = 0; g < 32; g++) {
      float4 X0 = *(float4*)&Us[wave * 2 + 0][g * 4];
      float4 X1 = *(float4*)&Us[wave * 2 + 1][g * 4];
      float4 w = *(const float4*)&W2Pl[g * 256 + lane * 4];
      v0 = fmaf(X0.x, w.x, v0); v0 = fmaf(X0.y, w.y, v0);
      v0 = fmaf(X0.z, w.z, v0); v0 = fmaf(X0.w, w.w, v0);
      v1 = fmaf(X1.x, w.x, v1); v1 = fmaf(X1.y, w.y, v1);
      v1 = fmaf(X1.z, w.z, v1); v1 = fmaf(X1.w, w.w, v1);
    }
    float g = lngn[lane], bgn = lnbn[lane];
    #pragma unroll
    for (int i = 0; i < 2; i++) {
      int gn = nb0 + i;
      float add = (i == 0) ? v0 : v1;
      float hv = h[gn * H + lane] + add;
      h[gn * H + lane] = hv;
      if (l != NLAYERS - 1) {
        float s = hv, q = hv * hv;
        #pragma unroll
        for (int m = 1; m < 64; m <<= 1) { s += __shfl_xor(s, m); q += __shfl_xor(q, m); }
        float mu = s * (1.0f / 64.0f);
        float var = q * (1.0f / 64.0f) - mu * mu;
        float rs = rsqrtf(var + 1e-5f);
        zn[gn * H + lane] = fmaxf(fmaf((hv - mu) * rs, g, bgn), 0.f);
      }
    }
  }
}

// ---------------- head: out = h @ Wh + bh ----------------
__global__ __launch_bounds__(256) void k_head(const float* __restrict__ h, const float* __restrict__ Wh,
                                              const float* __restrict__ bh, float* __restrict__ out) {
  __shared__ float Hs[8][H];
  int t = threadIdx.x;
  int tile = blockIdx.x * 8;
  if (t < 128) {
    int r = t >> 4, c4 = t & 15;
    float4 v = ((const float4*)h)[(tile + r) * 16 + c4];
    *(float4*)&Hs[r][c4 * 4] = v;
  }
  __syncthreads();
  int lane = t & 63;
  int wave = __builtin_amdgcn_readfirstlane(t >> 6);
  int n0 = wave * 2;
  int c2 = 64 + ((lane < 48) ? lane : 47);   // safe address; discarded if lane>=48
  float b0 = bh[lane], b1 = bh[c2];
  float a00 = b0, a01 = b1, a10 = b0, a11 = b1;
  #pragma unroll
  for (int k = 0; k < H; k += 4) {
    float4 X0 = *(float4*)&Hs[n0][k];
    float4 X1 = *(float4*)&Hs[n0 + 1][k];
    float wA0 = Wh[(k + 0) * OUT_CH + lane], wB0 = Wh[(k + 0) * OUT_CH + c2];
    float wA1 = Wh[(k + 1) * OUT_CH + lane], wB1 = Wh[(k + 1) * OUT_CH + c2];
    float wA2 = Wh[(k + 2) * OUT_CH + lane], wB2 = Wh[(k + 2) * OUT_CH + c2];
    float wA3 = Wh[(k + 3) * OUT_CH + lane], wB3 = Wh[(k + 3) * OUT_CH + c2];
    a00 = fmaf(X0.x, wA0, a00); a01 = fmaf(X0.x, wB0, a01);
    a00 = fmaf(X0.y, wA1, a00); a01 = fmaf(X0.y, wB1, a01);
    a00 = fmaf(X0.z, wA2, a00); a01 = fmaf(X0.z, wB2, a01);
    a00 = fmaf(X0.w, wA3, a00); a01 = fmaf(X0.w, wB3, a01);
    a10 = fmaf(X1.x, wA0, a10); a11 = fmaf(X1.x, wB0, a11);
    a10 = fmaf(X1.y, wA1, a10); a11 = fmaf(X1.y, wB1, a11);
    a10 = fmaf(X1.z, wA2, a10); a11 = fmaf(X1.z, wB2, a11);
    a10 = fmaf(X1.w, wA3, a10); a11 = fmaf(X1.w, wB3, a11);
  }
  int gn0 = tile + n0;
  out[gn0 * OUT_CH + lane] = a00;
  out[(gn0 + 1) * OUT_CH + lane] = a10;
  if (lane < 48) {
    out[gn0 * OUT_CH + 64 + lane] = a01;
    out[(gn0 + 1) * OUT_CH + 64 + lane] = a11;
  }
}

extern "C" void kernel_launch(void* const* d_in, const int* in_sizes, int n_in,
                              void* d_out, int out_size, void* d_ws, size_t ws_size,
                              hipStream_t stream) {
  (void)in_sizes; (void)n_in; (void)out_size; (void)ws_size;
  const float* x    = (const float*)d_in[0];
  const int*   ei   = (const int*)d_in[1];
  const float* encW = (const float*)d_in[2];
  const float* encb = (const float*)d_in[3];
  const float* lng  = (const float*)d_in[4];
  const float* lnb  = (const float*)d_in[5];
  const float* tv   = (const float*)d_in[6];
  const float* W1   = (const float*)d_in[7];
  const float* b1   = (const float*)d_in[8];
  const float* mg   = (const float*)d_in[9];
  const float* mb   = (const float*)d_in[10];
  const float* W2   = (const float*)d_in[11];
  const float* b2   = (const float*)d_in[12];
  const float* Wh   = (const float*)d_in[13];
  const float* bh   = (const float*)d_in[14];

  char* ws = (char*)d_ws;
  int*   deg  = (int*)(ws + 0);           // N ints
  int*   cur  = (int*)(ws + 40000);       // N ints
  int*   offs = (int*)(ws + 80000);       // N+1 ints
  int*   csr  = (int*)(ws + 120064);      // E ints
  float* h    = (float*)(ws + 760064);    // N*64
  float* z0   = (float*)(ws + 3320064);   // N*64
  float* z1   = (float*)(ws + 5880064);   // N*64
  float* W1P  = (float*)(ws + 8440064);   // 28*8192
  float* W2P  = (float*)(ws + 9357568);   // 28*8192  (end: 10275072)

  hipMemsetAsync(ws, 0, 80000, stream);   // deg + cur
  k_count<<<625, 256, 0, stream>>>(ei, deg);
  k_pack<<<28, 256, 0, stream>>>(W1, W2, W1P, W2P);
  k_scan<<<1, 1024, 0, stream>>>(deg, offs);
  k_fill<<<625, 256, 0, stream>>>(ei, offs, cur, csr);
  k_encoder<<<1250, 256, 0, stream>>>(x, encW, encb, lng, lnb, h, z0);

  float* zc = z0;
  float* znx = z1;
  for (int l = 0; l < NLAYERS; l++) {
    int ln_next = (l + 1 < NLAYERS) ? (l + 1) : l;
    k_layer<<<1250, 256, 0, stream>>>(zc, znx, h, offs, csr, tv,
                                      W1P, b1, mg, mb, W2P, b2,
                                      lng + ln_next * H, lnb + ln_next * H, l);
    float* tmp = zc; zc = znx; znx = tmp;
  }
  k_head<<<1250, 256, 0, stream>>>(h, Wh, bh, (float*)d_out);
}